// Round 5
// baseline (1673.229 us; speedup 1.0000x reference)
//
#include <hip/hip_runtime.h>

#define NN 100000
#define NE 1600000
#define DD 128
#define NCB 49      // coarse buckets, 2048 nodes each (dst >> 11)
#define NFB 782     // fine buckets, 128 nodes each = ceil(NN/128)
#define TILE 2048   // edges per hist/scatter tile
#define NTILE 782   // ceil(NE/TILE)

typedef __attribute__((ext_vector_type(8))) short bf16x8;
typedef __attribute__((ext_vector_type(4))) float f32x4;

union u4bf8 { uint4 u; bf16x8 v; };

__device__ __forceinline__ ushort f2bf(float f) {
    union { float f; uint i; } v; v.f = f;
    uint i = v.i;
    return (ushort)((i + 0x7fffu + ((i >> 16) & 1u)) >> 16);
}
__device__ __forceinline__ float bf2f(ushort u) {
    union { uint i; float f; } v; v.i = ((uint)u) << 16; return v.f;
}

// xb[n*64+j] packs (feat j, feat j+64) as bf16x2; also zero ghistP + stats
__global__ void k_xb(const float* __restrict__ x, uint* __restrict__ xb,
                     int* __restrict__ ghistP, float* __restrict__ stats) {
    int gid = blockIdx.x * 256 + threadIdx.x;   // NN*16 threads
    if (gid < NCB * 16) ghistP[gid] = 0;
    else if (gid < NCB * 16 + 512) stats[gid - NCB * 16] = 0.f;
    int n = gid >> 4, j0 = (gid & 15) * 4;
    const float* xp = x + (size_t)n * DD + j0;
    float4 a = *(const float4*)xp;
    float4 b = *(const float4*)(xp + 64);
    uint4 pk;
    pk.x = (uint)f2bf(a.x) | ((uint)f2bf(b.x) << 16);
    pk.y = (uint)f2bf(a.y) | ((uint)f2bf(b.y) << 16);
    pk.z = (uint)f2bf(a.z) | ((uint)f2bf(b.z) << 16);
    pk.w = (uint)f2bf(a.w) | ((uint)f2bf(b.w) << 16);
    *(uint4*)(xb + (size_t)n * 64 + j0) = pk;
}

// coarse histogram: LDS per tile, 49 global atomics per tile
__global__ __launch_bounds__(256) void k_chist(const int* __restrict__ ei,
                                               int* __restrict__ ghistP) {
    __shared__ int h[NCB];
    int t = threadIdx.x;
    if (t < NCB) h[t] = 0;
    __syncthreads();
    int base = blockIdx.x * TILE;
#pragma unroll
    for (int i = 0; i < 8; ++i) {
        int e = base + i * 256 + t;
        if (e < NE) atomicAdd(&h[ei[NE + e] >> 11], 1);
    }
    __syncthreads();
    if (t < NCB && h[t] > 0) atomicAdd(&ghistP[t * 16], h[t]);
}

// exclusive scan of 49 coarse counts -> cb[0..49], init cursors
__global__ void k_cscan(const int* __restrict__ ghistP, int* __restrict__ cb,
                        int* __restrict__ gcurP) {
    __shared__ int sh[NCB + 1];
    int t = threadIdx.x;   // 64 threads
    if (t < NCB) sh[t] = ghistP[t * 16];
    __syncthreads();
    if (t == 0) {
        int run = 0;
        for (int i = 0; i < NCB; ++i) { int c = sh[i]; sh[i] = run; run += c; }
        sh[NCB] = run;
    }
    __syncthreads();
    if (t < NCB) { cb[t] = sh[t]; gcurP[t * 16] = sh[t]; }
    if (t == NCB) cb[NCB] = sh[NCB];
}

// bucketize edges by coarse dst; packed val = src | (dst&2047)<<17
__global__ __launch_bounds__(256) void k_cscatter(const int* __restrict__ ei,
                                                  int* __restrict__ gcurP,
                                                  uint* __restrict__ buck) {
    __shared__ int h[NCB];
    __shared__ int tb[NCB];
    int t = threadIdx.x;
    if (t < NCB) h[t] = 0;
    __syncthreads();
    int base = blockIdx.x * TILE;
    uint vv[8]; int bb[8], rr[8];
#pragma unroll
    for (int i = 0; i < 8; ++i) {
        int e = base + i * 256 + t;
        bb[i] = -1;
        if (e < NE) {
            int s = ei[e], d = ei[NE + e];
            int b = d >> 11;
            bb[i] = b;
            vv[i] = (uint)s | ((uint)(d & 2047) << 17);
            rr[i] = atomicAdd(&h[b], 1);
        }
    }
    __syncthreads();
    if (t < NCB && h[t] > 0) tb[t] = atomicAdd(&gcurP[t * 16], h[t]);
    __syncthreads();
#pragma unroll
    for (int i = 0; i < 8; ++i) {
        if (bb[i] >= 0) buck[tb[bb[i]] + rr[i]] = vv[i];
    }
}

// block = 128-node window; scan coarse segment, ballot-filter, LDS fp32 accumulate
__global__ __launch_bounds__(256) void k_accum(const float* __restrict__ x,
                                               const uint* __restrict__ xb,
                                               const int* __restrict__ cb,
                                               const uint* __restrict__ buck,
                                               ushort* __restrict__ agg) {
    __shared__ float acc[DD][DD];   // acc[row][feat], 64 KB
    int tid = threadIdx.x, lane = tid & 63;
    float4 z = {0.f, 0.f, 0.f, 0.f};
#pragma unroll
    for (int i = 0; i < 16; ++i) ((float4*)acc)[i * 256 + tid] = z;
    __syncthreads();

    int fine = blockIdx.x;
    int coarse = fine >> 4, sub = fine & 15;
    int start = cb[coarse], end = cb[coarse + 1];
    int iters = (end - start + 255) >> 8;
    for (int it = 0; it < iters; ++it) {
        int idx = start + it * 256 + tid;
        uint val = 0xFFFFFFFFu;
        if (idx < end) val = buck[idx];
        bool match = (val >> 24) == (uint)sub;
        unsigned long long mask = __ballot(match);
        while (mask) {
            int l = __ffsll(mask) - 1;
            mask &= mask - 1;
            uint v = (uint)__shfl((int)val, l, 64);
            uint srcj = v & 0x1FFFFu;
            int row = (int)((v >> 17) & 127u);
            uint pk = xb[(size_t)srcj * 64 + lane];
            atomicAdd(&acc[row][lane],      bf2f((ushort)(pk & 0xffffu)));
            atomicAdd(&acc[row][lane + 64], bf2f((ushort)(pk >> 16)));
        }
    }
    __syncthreads();

    int n0 = fine * 128;
#pragma unroll
    for (int i = 0; i < 32; ++i) {
        int li = i * 256 + tid;      // 128 rows x 64
        int r = li >> 6, j = li & 63;
        int n = n0 + r;
        if (n < NN) {
            float f0 = acc[r][j]      + x[(size_t)n * DD + j];
            float f1 = acc[r][j + 64] + x[(size_t)n * DD + j + 64];
            agg[(size_t)n * DD + j]      = f2bf(f0);
            agg[(size_t)n * DD + j + 64] = f2bf(f1);
        }
    }
}

// MODE 1: A = bf16 agg, no pre-transform, bias, bf16 out, emit colstats
// MODE 2: A = bf16 t1,  pre-transform relu(a*t+c), bias, bf16 out, emit colstats
// MODE 3: A = bf16 t2,  pre-transform relu(a*t+c), no bias, relu, fp32 out, no stats
template <int MODE>
__global__ __launch_bounds__(256) void k_gemm(const ushort* __restrict__ Ain,
                                              const float* __restrict__ W,
                                              const float* __restrict__ bias,
                                              const float* __restrict__ ac,
                                              void* __restrict__ Outv,
                                              float* __restrict__ stats) {
    __shared__ ushort lw[DD * 136];
    __shared__ float red[2][4][DD];

    int tid = threadIdx.x;
#pragma unroll
    for (int it = 0; it < 8; ++it) {
        int idx = (it * 256 + tid) * 8;
        int r = idx >> 7, k = idx & 127;
        float4 u0 = *(const float4*)(W + idx);
        float4 u1 = *(const float4*)(W + idx + 4);
        uint4 pk;
        pk.x = (uint)f2bf(u0.x) | ((uint)f2bf(u0.y) << 16);
        pk.y = (uint)f2bf(u0.z) | ((uint)f2bf(u0.w) << 16);
        pk.z = (uint)f2bf(u1.x) | ((uint)f2bf(u1.y) << 16);
        pk.w = (uint)f2bf(u1.z) | ((uint)f2bf(u1.w) << 16);
        *(uint4*)&lw[r * 136 + k] = pk;
    }
    __syncthreads();

    int wave = tid >> 6, lane = tid & 63;
    int lm = lane & 15, quad = lane >> 4;
    int row0 = blockIdx.x * 64 + wave * 16;
    int arow = row0 + lm;
    int ar = (arow < NN) ? arow : 0;

    bf16x8 afrag[4];
#pragma unroll
    for (int kb = 0; kb < 4; ++kb) {
        int k0 = kb * 32 + quad * 8;
        const ushort* ap = Ain + (size_t)ar * DD + k0;
        u4bf8 u; u.u = *(const uint4*)ap;
        if constexpr (MODE == 1) {
            afrag[kb] = u.v;
        } else {
            uint pk[4] = {u.u.x, u.u.y, u.u.z, u.u.w};
            bf16x8 af;
#pragma unroll
            for (int jj = 0; jj < 4; ++jj) {
                int k = k0 + jj * 2;
                float v0 = bf2f((ushort)(pk[jj] & 0xffffu));
                float v1 = bf2f((ushort)(pk[jj] >> 16));
                v0 = fmaxf(fmaf(v0, ac[k], ac[DD + k]), 0.f);
                v1 = fmaxf(fmaf(v1, ac[k + 1], ac[DD + k + 1]), 0.f);
                af[jj * 2]     = (short)f2bf(v0);
                af[jj * 2 + 1] = (short)f2bf(v1);
            }
            afrag[kb] = af;
        }
    }

    f32x4 acc[8];
#pragma unroll
    for (int nt = 0; nt < 8; ++nt) {
        float bv = (MODE == 3) ? 0.f : bias[nt * 16 + lm];
        acc[nt] = (f32x4){bv, bv, bv, bv};
    }

#pragma unroll
    for (int kb = 0; kb < 4; ++kb) {
#pragma unroll
        for (int nt = 0; nt < 8; ++nt) {
            bf16x8 bfrag = *(const bf16x8*)&lw[(nt * 16 + lm) * 136 + kb * 32 + quad * 8];
            acc[nt] = __builtin_amdgcn_mfma_f32_16x16x32_bf16(afrag[kb], bfrag, acc[nt], 0, 0, 0);
        }
    }

    ushort* Out16 = (ushort*)Outv;
    float* Out32 = (float*)Outv;
    float csum[8], csq[8];
#pragma unroll
    for (int nt = 0; nt < 8; ++nt) {
        int col = nt * 16 + lm;
        float s = 0.f, q = 0.f;
#pragma unroll
        for (int r = 0; r < 4; ++r) {
            int row = row0 + quad * 4 + r;
            float v = acc[nt][r];
            if (MODE == 3) v = fmaxf(v, 0.f);
            if (row < NN) {
                if constexpr (MODE == 3) Out32[(size_t)row * DD + col] = v;
                else Out16[(size_t)row * DD + col] = f2bf(v);
                s += v;
                q += v * v;
            }
        }
        csum[nt] = s; csq[nt] = q;
    }

    if constexpr (MODE != 3) {
#pragma unroll
        for (int nt = 0; nt < 8; ++nt) {
            float s = csum[nt], q = csq[nt];
            s += __shfl_down(s, 16, 64); q += __shfl_down(q, 16, 64);
            s += __shfl_down(s, 32, 64); q += __shfl_down(q, 32, 64);
            if (quad == 0) {
                red[0][wave][nt * 16 + lm] = s;
                red[1][wave][nt * 16 + lm] = q;
            }
        }
        __syncthreads();
        if (tid < DD) {
            float S = red[0][0][tid] + red[0][1][tid] + red[0][2][tid] + red[0][3][tid];
            float Q = red[1][0][tid] + red[1][1][tid] + red[1][2][tid] + red[1][3][tid];
            atomicAdd(&stats[tid], S);
            atomicAdd(&stats[DD + tid], Q);
        }
    }
}

__global__ void k_finalize(const float* __restrict__ stats, const float* __restrict__ g,
                           const float* __restrict__ be, float* __restrict__ ac) {
    int c = threadIdx.x;
    float inv = 1.f / (float)NN;
    float mean = stats[c] * inv;
    float var = stats[DD + c] * inv - mean * mean;
    float a = g[c] * rsqrtf(var + 1e-5f);
    ac[c] = a;
    ac[DD + c] = be[c] - mean * a;
}

extern "C" void kernel_launch(void* const* d_in, const int* in_sizes, int n_in,
                              void* d_out, int out_size, void* d_ws, size_t ws_size,
                              hipStream_t stream) {
    const float* x   = (const float*)d_in[0];
    const int* ei    = (const int*)d_in[1];
    const float* W1  = (const float*)d_in[2];
    const float* b1  = (const float*)d_in[3];
    const float* g1  = (const float*)d_in[4];
    const float* be1 = (const float*)d_in[5];
    const float* W2  = (const float*)d_in[6];
    const float* b2  = (const float*)d_in[7];
    const float* g2  = (const float*)d_in[8];
    const float* be2 = (const float*)d_in[9];
    const float* W3  = (const float*)d_in[10];

    // ws: stats[512] | ac[512] | ghistP[49*16] | cb[64] | gcurP[49*16]
    //   | buck u32[NE] | agg bf16[NN*DD] (reused as t2)     ~32 MB
    float* stats = (float*)d_ws;
    float* ac    = stats + 512;
    int* ghistP  = (int*)(ac + 512);
    int* cb      = ghistP + NCB * 16;
    int* gcurP   = cb + 64;
    uint* buck   = (uint*)(gcurP + NCB * 16);
    ushort* agg  = (ushort*)(buck + NE);
    // d_out: first half = xb (repacked bf16 x), second half = t1
    uint* xb     = (uint*)d_out;
    ushort* t1   = (ushort*)d_out + (size_t)NN * DD;
    ushort* t2   = agg;
    float* outp  = (float*)d_out;

    int gblk = (NN + 63) / 64;
    k_xb<<<NN * 16 / 256, 256, 0, stream>>>(x, xb, ghistP, stats);
    k_chist<<<NTILE, 256, 0, stream>>>(ei, ghistP);
    k_cscan<<<1, 64, 0, stream>>>(ghistP, cb, gcurP);
    k_cscatter<<<NTILE, 256, 0, stream>>>(ei, gcurP, buck);
    k_accum<<<NFB, 256, 0, stream>>>(x, xb, cb, buck, agg);
    k_gemm<1><<<gblk, 256, 0, stream>>>(agg, W1, b1, nullptr, t1, stats);
    k_finalize<<<1, DD, 0, stream>>>(stats, g1, be1, ac);
    k_gemm<2><<<gblk, 256, 0, stream>>>(t1, W2, b2, ac, t2, stats + 256);
    k_finalize<<<1, DD, 0, stream>>>(stats + 256, g2, be2, ac + 256);
    k_gemm<3><<<gblk, 256, 0, stream>>>(t2, W3, nullptr, ac + 256, outp, nullptr);
}

// Round 6
// 381.671 us; speedup vs baseline: 4.3840x; 4.3840x over previous
//
#include <hip/hip_runtime.h>

#define NN 100000
#define NE 1600000
#define DD 128
#define NCB 196     // coarse buckets, 512 nodes each (dst >> 9)
#define TILE 2048   // edges per hist/scatter tile
#define NTILE 782   // ceil(NE/TILE)

typedef __attribute__((ext_vector_type(8))) short bf16x8;
typedef __attribute__((ext_vector_type(4))) float f32x4;

union u4bf8 { uint4 u; bf16x8 v; };

__device__ __forceinline__ ushort f2bf(float f) {
    union { float f; uint i; } v; v.f = f;
    uint i = v.i;
    return (ushort)((i + 0x7fffu + ((i >> 16) & 1u)) >> 16);
}
__device__ __forceinline__ float bf2f(ushort u) {
    union { uint i; float f; } v; v.i = ((uint)u) << 16; return v.f;
}

// xb = bf16 copy of x (contiguous row layout); zero ghistP + stats
__global__ void k_xb(const float* __restrict__ x, uint* __restrict__ xb,
                     int* __restrict__ ghistP, float* __restrict__ stats) {
    int gid = blockIdx.x * 256 + threadIdx.x;   // NN*16 threads
    if (gid < NCB * 16) ghistP[gid] = 0;
    else if (gid < NCB * 16 + 512) stats[gid - NCB * 16] = 0.f;
    int n = gid >> 4, j0 = (gid & 15) * 8;
    const float* xp = x + (size_t)n * DD + j0;
    float4 a = *(const float4*)xp;
    float4 b = *(const float4*)(xp + 4);
    uint4 pk;
    pk.x = (uint)f2bf(a.x) | ((uint)f2bf(a.y) << 16);
    pk.y = (uint)f2bf(a.z) | ((uint)f2bf(a.w) << 16);
    pk.z = (uint)f2bf(b.x) | ((uint)f2bf(b.y) << 16);
    pk.w = (uint)f2bf(b.z) | ((uint)f2bf(b.w) << 16);
    *(uint4*)(xb + (size_t)n * 64 + (gid & 15) * 4) = pk;
}

// coarse histogram: LDS per tile, NCB global atomics per tile
__global__ __launch_bounds__(256) void k_chist(const int* __restrict__ ei,
                                               int* __restrict__ ghistP) {
    __shared__ int h[NCB];
    int t = threadIdx.x;
    if (t < NCB) h[t] = 0;
    __syncthreads();
    int base = blockIdx.x * TILE;
#pragma unroll
    for (int i = 0; i < 8; ++i) {
        int e = base + i * 256 + t;
        if (e < NE) atomicAdd(&h[ei[NE + e] >> 9], 1);
    }
    __syncthreads();
    if (t < NCB && h[t] > 0) atomicAdd(&ghistP[t * 16], h[t]);
}

// exclusive scan of NCB coarse counts -> cb[0..NCB], init cursors
__global__ void k_cscan(const int* __restrict__ ghistP, int* __restrict__ cb,
                        int* __restrict__ gcurP) {
    __shared__ int sh[NCB + 1];
    int t = threadIdx.x;   // 256 threads
    if (t < NCB) sh[t] = ghistP[t * 16];
    __syncthreads();
    if (t == 0) {
        int run = 0;
        for (int i = 0; i < NCB; ++i) { int c = sh[i]; sh[i] = run; run += c; }
        sh[NCB] = run;
    }
    __syncthreads();
    if (t < NCB) { cb[t] = sh[t]; gcurP[t * 16] = sh[t]; }
    if (t == NCB) cb[NCB] = sh[NCB];
}

// bucketize edges by coarse dst; packed val = src | (dst&511)<<17
__global__ __launch_bounds__(256) void k_cscatter(const int* __restrict__ ei,
                                                  int* __restrict__ gcurP,
                                                  uint* __restrict__ buck) {
    __shared__ int h[NCB];
    __shared__ int tb[NCB];
    int t = threadIdx.x;
    if (t < NCB) h[t] = 0;
    __syncthreads();
    int base = blockIdx.x * TILE;
    uint vv[8]; int bb[8], rr[8];
#pragma unroll
    for (int i = 0; i < 8; ++i) {
        int e = base + i * 256 + t;
        bb[i] = -1;
        if (e < NE) {
            int s = ei[e], d = ei[NE + e];
            int b = d >> 9;
            bb[i] = b;
            vv[i] = (uint)s | ((uint)(d & 511) << 17);
            rr[i] = atomicAdd(&h[b], 1);
        }
    }
    __syncthreads();
    if (t < NCB && h[t] > 0) tb[t] = atomicAdd(&gcurP[t * 16], h[t]);
    __syncthreads();
#pragma unroll
    for (int i = 0; i < 8; ++i) {
        if (bb[i] >= 0) buck[tb[bb[i]] + rr[i]] = vv[i];
    }
}

// one block per coarse bucket: fine 512-node hist + scan in LDS, write rowp,
// scatter segment into node-sorted csr (single-owner 32KB region)
__global__ __launch_bounds__(256) void k_fsort(const uint* __restrict__ buck,
                                               const int* __restrict__ cb,
                                               int* __restrict__ csr,
                                               int* __restrict__ rowp) {
    __shared__ int cnt[512];
    __shared__ int sd[256];
    int c = blockIdx.x, t = threadIdx.x;
    cnt[t] = 0; cnt[t + 256] = 0;
    __syncthreads();
    int s0 = cb[c], s1 = cb[c + 1];
    for (int i = s0 + t; i < s1; i += 256)
        atomicAdd(&cnt[(buck[i] >> 17) & 511], 1);
    __syncthreads();
    int p = cnt[2 * t], q = cnt[2 * t + 1];
    sd[t] = p + q;
    __syncthreads();
    for (int o = 1; o < 256; o <<= 1) {
        int u = (t >= o) ? sd[t - o] : 0;
        __syncthreads();
        sd[t] += u;
        __syncthreads();
    }
    int base = sd[t] - (p + q);   // exclusive over pairs
    rowp[c * 512 + 2 * t]     = s0 + base;
    rowp[c * 512 + 2 * t + 1] = s0 + base + p;
    __syncthreads();
    cnt[2 * t] = base;
    cnt[2 * t + 1] = base + p;
    __syncthreads();
    for (int i = s0 + t; i < s1; i += 256) {
        uint v = buck[i];
        int ld = (int)((v >> 17) & 511u);
        int pos = atomicAdd(&cnt[ld], 1);
        csr[s0 + pos] = (int)(v & 0x1FFFFu);
    }
}

// one wave per node: agg[n] = x[n] (fp32) + sum_{j in CSR[n]} xb[j] (bf16 rows)
__global__ __launch_bounds__(256) void k_gather(const float* __restrict__ x,
                                                const uint* __restrict__ xb,
                                                const int* __restrict__ rowp,
                                                const int* __restrict__ csr,
                                                ushort* __restrict__ agg) {
    int wave = threadIdx.x >> 6, lane = threadIdx.x & 63;
    int n = blockIdx.x * 4 + wave;
    if (n >= NN) return;
    float2 sv = ((const float2*)(x + (size_t)n * DD))[lane];
    float a0 = sv.x, a1 = sv.y;
    int rs = rowp[n], re = rowp[n + 1];
    int i = rs;
    for (; i + 4 <= re; i += 4) {
        int s0 = csr[i], s1 = csr[i + 1], s2 = csr[i + 2], s3 = csr[i + 3];
        uint v0 = xb[(size_t)s0 * 64 + lane];
        uint v1 = xb[(size_t)s1 * 64 + lane];
        uint v2 = xb[(size_t)s2 * 64 + lane];
        uint v3 = xb[(size_t)s3 * 64 + lane];
        a0 += bf2f((ushort)(v0 & 0xffffu)) + bf2f((ushort)(v1 & 0xffffu))
            + bf2f((ushort)(v2 & 0xffffu)) + bf2f((ushort)(v3 & 0xffffu));
        a1 += bf2f((ushort)(v0 >> 16)) + bf2f((ushort)(v1 >> 16))
            + bf2f((ushort)(v2 >> 16)) + bf2f((ushort)(v3 >> 16));
    }
    for (; i < re; ++i) {
        uint v = xb[(size_t)csr[i] * 64 + lane];
        a0 += bf2f((ushort)(v & 0xffffu));
        a1 += bf2f((ushort)(v >> 16));
    }
    uint pk = (uint)f2bf(a0) | ((uint)f2bf(a1) << 16);
    ((uint*)(agg + (size_t)n * DD))[lane] = pk;
}

// MODE 1: A = bf16 agg, no pre-transform, bias, bf16 out, emit colstats
// MODE 2: A = bf16 t1,  pre-transform relu(a*t+c), bias, bf16 out, emit colstats
// MODE 3: A = bf16 t2,  pre-transform relu(a*t+c), no bias, relu, fp32 out, no stats
template <int MODE>
__global__ __launch_bounds__(256) void k_gemm(const ushort* __restrict__ Ain,
                                              const float* __restrict__ W,
                                              const float* __restrict__ bias,
                                              const float* __restrict__ ac,
                                              void* __restrict__ Outv,
                                              float* __restrict__ stats) {
    __shared__ ushort lw[DD * 136];
    __shared__ float red[2][4][DD];

    int tid = threadIdx.x;
#pragma unroll
    for (int it = 0; it < 8; ++it) {
        int idx = (it * 256 + tid) * 8;
        int r = idx >> 7, k = idx & 127;
        float4 u0 = *(const float4*)(W + idx);
        float4 u1 = *(const float4*)(W + idx + 4);
        uint4 pk;
        pk.x = (uint)f2bf(u0.x) | ((uint)f2bf(u0.y) << 16);
        pk.y = (uint)f2bf(u0.z) | ((uint)f2bf(u0.w) << 16);
        pk.z = (uint)f2bf(u1.x) | ((uint)f2bf(u1.y) << 16);
        pk.w = (uint)f2bf(u1.z) | ((uint)f2bf(u1.w) << 16);
        *(uint4*)&lw[r * 136 + k] = pk;
    }
    __syncthreads();

    int wave = tid >> 6, lane = tid & 63;
    int lm = lane & 15, quad = lane >> 4;
    int row0 = blockIdx.x * 64 + wave * 16;
    int arow = row0 + lm;
    int ar = (arow < NN) ? arow : 0;

    bf16x8 afrag[4];
#pragma unroll
    for (int kb = 0; kb < 4; ++kb) {
        int k0 = kb * 32 + quad * 8;
        const ushort* ap = Ain + (size_t)ar * DD + k0;
        u4bf8 u; u.u = *(const uint4*)ap;
        if constexpr (MODE == 1) {
            afrag[kb] = u.v;
        } else {
            uint pk[4] = {u.u.x, u.u.y, u.u.z, u.u.w};
            bf16x8 af;
#pragma unroll
            for (int jj = 0; jj < 4; ++jj) {
                int k = k0 + jj * 2;
                float v0 = bf2f((ushort)(pk[jj] & 0xffffu));
                float v1 = bf2f((ushort)(pk[jj] >> 16));
                v0 = fmaxf(fmaf(v0, ac[k], ac[DD + k]), 0.f);
                v1 = fmaxf(fmaf(v1, ac[k + 1], ac[DD + k + 1]), 0.f);
                af[jj * 2]     = (short)f2bf(v0);
                af[jj * 2 + 1] = (short)f2bf(v1);
            }
            afrag[kb] = af;
        }
    }

    f32x4 acc[8];
#pragma unroll
    for (int nt = 0; nt < 8; ++nt) {
        float bv = (MODE == 3) ? 0.f : bias[nt * 16 + lm];
        acc[nt] = (f32x4){bv, bv, bv, bv};
    }

#pragma unroll
    for (int kb = 0; kb < 4; ++kb) {
#pragma unroll
        for (int nt = 0; nt < 8; ++nt) {
            bf16x8 bfrag = *(const bf16x8*)&lw[(nt * 16 + lm) * 136 + kb * 32 + quad * 8];
            acc[nt] = __builtin_amdgcn_mfma_f32_16x16x32_bf16(afrag[kb], bfrag, acc[nt], 0, 0, 0);
        }
    }

    ushort* Out16 = (ushort*)Outv;
    float* Out32 = (float*)Outv;
    float csum[8], csq[8];
#pragma unroll
    for (int nt = 0; nt < 8; ++nt) {
        int col = nt * 16 + lm;
        float s = 0.f, q = 0.f;
#pragma unroll
        for (int r = 0; r < 4; ++r) {
            int row = row0 + quad * 4 + r;
            float v = acc[nt][r];
            if (MODE == 3) v = fmaxf(v, 0.f);
            if (row < NN) {
                if constexpr (MODE == 3) Out32[(size_t)row * DD + col] = v;
                else Out16[(size_t)row * DD + col] = f2bf(v);
                s += v;
                q += v * v;
            }
        }
        csum[nt] = s; csq[nt] = q;
    }

    if constexpr (MODE != 3) {
#pragma unroll
        for (int nt = 0; nt < 8; ++nt) {
            float s = csum[nt], q = csq[nt];
            s += __shfl_down(s, 16, 64); q += __shfl_down(q, 16, 64);
            s += __shfl_down(s, 32, 64); q += __shfl_down(q, 32, 64);
            if (quad == 0) {
                red[0][wave][nt * 16 + lm] = s;
                red[1][wave][nt * 16 + lm] = q;
            }
        }
        __syncthreads();
        if (tid < DD) {
            float S = red[0][0][tid] + red[0][1][tid] + red[0][2][tid] + red[0][3][tid];
            float Q = red[1][0][tid] + red[1][1][tid] + red[1][2][tid] + red[1][3][tid];
            atomicAdd(&stats[tid], S);
            atomicAdd(&stats[DD + tid], Q);
        }
    }
}

__global__ void k_finalize(const float* __restrict__ stats, const float* __restrict__ g,
                           const float* __restrict__ be, float* __restrict__ ac) {
    int c = threadIdx.x;
    float inv = 1.f / (float)NN;
    float mean = stats[c] * inv;
    float var = stats[DD + c] * inv - mean * mean;
    float a = g[c] * rsqrtf(var + 1e-5f);
    ac[c] = a;
    ac[DD + c] = be[c] - mean * a;
}

extern "C" void kernel_launch(void* const* d_in, const int* in_sizes, int n_in,
                              void* d_out, int out_size, void* d_ws, size_t ws_size,
                              hipStream_t stream) {
    const float* x   = (const float*)d_in[0];
    const int* ei    = (const int*)d_in[1];
    const float* W1  = (const float*)d_in[2];
    const float* b1  = (const float*)d_in[3];
    const float* g1  = (const float*)d_in[4];
    const float* be1 = (const float*)d_in[5];
    const float* W2  = (const float*)d_in[6];
    const float* b2  = (const float*)d_in[7];
    const float* g2  = (const float*)d_in[8];
    const float* be2 = (const float*)d_in[9];
    const float* W3  = (const float*)d_in[10];

    // ws: stats[512] | ac[512] | ghistP[NCB*16] | cb[NCB+4] | gcurP[NCB*16]
    //   | rowp i32[NCB*512+4] | buck u32[NE] | csr i32[NE]
    //   | agg bf16[NN*DD] (reused as t2)        ~39 MB
    float* stats = (float*)d_ws;
    float* ac    = stats + 512;
    int* ghistP  = (int*)(ac + 512);
    int* cb      = ghistP + NCB * 16;
    int* gcurP   = cb + NCB + 4;
    int* rowp    = gcurP + NCB * 16;
    uint* buck   = (uint*)(rowp + NCB * 512 + 4);
    int* csr     = (int*)(buck + NE);
    ushort* agg  = (ushort*)(csr + NE);
    // d_out: first half = xb (bf16 x copy), second half = t1
    uint* xb     = (uint*)d_out;
    ushort* t1   = (ushort*)d_out + (size_t)NN * DD;
    ushort* t2   = agg;
    float* outp  = (float*)d_out;

    int gblk = (NN + 63) / 64;
    k_xb<<<NN * 16 / 256, 256, 0, stream>>>(x, xb, ghistP, stats);
    k_chist<<<NTILE, 256, 0, stream>>>(ei, ghistP);
    k_cscan<<<1, 256, 0, stream>>>(ghistP, cb, gcurP);
    k_cscatter<<<NTILE, 256, 0, stream>>>(ei, gcurP, buck);
    k_fsort<<<NCB, 256, 0, stream>>>(buck, cb, csr, rowp);
    k_gather<<<(NN + 3) / 4, 256, 0, stream>>>(x, xb, rowp, csr, agg);
    k_gemm<1><<<gblk, 256, 0, stream>>>(agg, W1, b1, nullptr, t1, stats);
    k_finalize<<<1, DD, 0, stream>>>(stats, g1, be1, ac);
    k_gemm<2><<<gblk, 256, 0, stream>>>(t1, W2, b2, ac, t2, stats + 256);
    k_finalize<<<1, DD, 0, stream>>>(stats + 256, g2, be2, ac + 256);
    k_gemm<3><<<gblk, 256, 0, stream>>>(t2, W3, nullptr, ac + 256, outp, nullptr);
}

// Round 7
// 359.842 us; speedup vs baseline: 4.6499x; 1.0607x over previous
//
#include <hip/hip_runtime.h>

#define NN 100000
#define NE 1600000
#define DD 128
#define NCB 196     // coarse buckets, 512 nodes each (dst >> 9)
#define TILE 2048   // edges per hist/scatter tile
#define NTILE 782   // ceil(NE/TILE)

typedef __attribute__((ext_vector_type(8))) short bf16x8;
typedef __attribute__((ext_vector_type(4))) float f32x4;

union u4bf8 { uint4 u; bf16x8 v; };

__device__ __forceinline__ ushort f2bf(float f) {
    union { float f; uint i; } v; v.f = f;
    uint i = v.i;
    return (ushort)((i + 0x7fffu + ((i >> 16) & 1u)) >> 16);
}
__device__ __forceinline__ float bf2f(ushort u) {
    union { uint i; float f; } v; v.i = ((uint)u) << 16; return v.f;
}
__device__ __forceinline__ float blo(uint v) { return bf2f((ushort)(v & 0xffffu)); }
__device__ __forceinline__ float bhi(uint v) { return bf2f((ushort)(v >> 16)); }

// fused: bf16 conversion of x -> xb  +  coarse dst histogram (LDS, NCB atomics/tile)
__global__ __launch_bounds__(256) void k_xbh(const float* __restrict__ x,
                                             uint* __restrict__ xb,
                                             const int* __restrict__ ei,
                                             int* __restrict__ ghistP) {
    __shared__ int h[NCB];
    int t = threadIdx.x;
    if (t < NCB) h[t] = 0;
    __syncthreads();
    int base = blockIdx.x * TILE;
#pragma unroll
    for (int i = 0; i < 8; ++i) {
        int e = base + i * 256 + t;
        if (e < NE) atomicAdd(&h[ei[NE + e] >> 9], 1);
    }
    int gid = blockIdx.x * 256 + t;
#pragma unroll
    for (int i = 0; i < 8; ++i) {
        int item = i * (NTILE * 256) + gid;
        if (item < NN * 16) {
            int n = item >> 4, q = item & 15;
            const float* xp = x + (size_t)n * DD + q * 8;
            float4 a = *(const float4*)xp;
            float4 b = *(const float4*)(xp + 4);
            uint4 pk;
            pk.x = (uint)f2bf(a.x) | ((uint)f2bf(a.y) << 16);
            pk.y = (uint)f2bf(a.z) | ((uint)f2bf(a.w) << 16);
            pk.z = (uint)f2bf(b.x) | ((uint)f2bf(b.y) << 16);
            pk.w = (uint)f2bf(b.z) | ((uint)f2bf(b.w) << 16);
            *(uint4*)(xb + (size_t)n * 64 + q * 4) = pk;
        }
    }
    __syncthreads();
    if (t < NCB && h[t] > 0) atomicAdd(&ghistP[t * 16], h[t]);
}

// exclusive scan of NCB coarse counts -> cb[0..NCB], init cursors
__global__ void k_cscan(const int* __restrict__ ghistP, int* __restrict__ cb,
                        int* __restrict__ gcurP) {
    __shared__ int sh[NCB + 1];
    int t = threadIdx.x;   // 256 threads
    if (t < NCB) sh[t] = ghistP[t * 16];
    __syncthreads();
    if (t == 0) {
        int run = 0;
        for (int i = 0; i < NCB; ++i) { int c = sh[i]; sh[i] = run; run += c; }
        sh[NCB] = run;
    }
    __syncthreads();
    if (t < NCB) { cb[t] = sh[t]; gcurP[t * 16] = sh[t]; }
    if (t == NCB) cb[NCB] = sh[NCB];
}

// bucketize edges by coarse dst; packed val = src | (dst&511)<<17
__global__ __launch_bounds__(256) void k_cscatter(const int* __restrict__ ei,
                                                  int* __restrict__ gcurP,
                                                  uint* __restrict__ buck) {
    __shared__ int h[NCB];
    __shared__ int tb[NCB];
    int t = threadIdx.x;
    if (t < NCB) h[t] = 0;
    __syncthreads();
    int base = blockIdx.x * TILE;
    uint vv[8]; int bb[8], rr[8];
#pragma unroll
    for (int i = 0; i < 8; ++i) {
        int e = base + i * 256 + t;
        bb[i] = -1;
        if (e < NE) {
            int s = ei[e], d = ei[NE + e];
            int b = d >> 9;
            bb[i] = b;
            vv[i] = (uint)s | ((uint)(d & 511) << 17);
            rr[i] = atomicAdd(&h[b], 1);
        }
    }
    __syncthreads();
    if (t < NCB && h[t] > 0) tb[t] = atomicAdd(&gcurP[t * 16], h[t]);
    __syncthreads();
#pragma unroll
    for (int i = 0; i < 8; ++i) {
        if (bb[i] >= 0) buck[tb[bb[i]] + rr[i]] = vv[i];
    }
}

// one block per coarse bucket: fine 512-node hist + scan in LDS, write rowp,
// scatter segment into node-sorted csr (single-owner region)
__global__ __launch_bounds__(256) void k_fsort(const uint* __restrict__ buck,
                                               const int* __restrict__ cb,
                                               int* __restrict__ csr,
                                               int* __restrict__ rowp) {
    __shared__ int cnt[512];
    __shared__ int sd[256];
    int c = blockIdx.x, t = threadIdx.x;
    cnt[t] = 0; cnt[t + 256] = 0;
    __syncthreads();
    int s0 = cb[c], s1 = cb[c + 1];
    for (int i = s0 + t; i < s1; i += 256)
        atomicAdd(&cnt[(buck[i] >> 17) & 511], 1);
    __syncthreads();
    int p = cnt[2 * t], q = cnt[2 * t + 1];
    sd[t] = p + q;
    __syncthreads();
    for (int o = 1; o < 256; o <<= 1) {
        int u = (t >= o) ? sd[t - o] : 0;
        __syncthreads();
        sd[t] += u;
        __syncthreads();
    }
    int base = sd[t] - (p + q);
    rowp[c * 512 + 2 * t]     = s0 + base;
    rowp[c * 512 + 2 * t + 1] = s0 + base + p;
    __syncthreads();
    cnt[2 * t] = base;
    cnt[2 * t + 1] = base + p;
    __syncthreads();
    for (int i = s0 + t; i < s1; i += 256) {
        uint v = buck[i];
        int ld = (int)((v >> 17) & 511u);
        int pos = atomicAdd(&cnt[ld], 1);
        csr[s0 + pos] = (int)(v & 0x1FFFFu);
    }
}

// one wave per node: agg[n] = xb[n] + sum_{j in CSR[n]} xb[j]  (all bf16 rows)
__global__ __launch_bounds__(256) void k_gather(const uint* __restrict__ xb,
                                                const int* __restrict__ rowp,
                                                const int* __restrict__ csr,
                                                ushort* __restrict__ agg) {
    int wave = threadIdx.x >> 6, lane = threadIdx.x & 63;
    int n = blockIdx.x * 4 + wave;
    if (n >= NN) return;
    uint self = xb[(size_t)n * 64 + lane];
    float a0 = blo(self), a1 = bhi(self);
    int rs = rowp[n], re = rowp[n + 1];
    for (int base = rs; base < re; base += 64) {
        int m = re - base; if (m > 64) m = 64;
        int sj = (lane < m) ? csr[base + lane] : 0;
        int j = 0;
        for (; j + 8 <= m; j += 8) {
            int s0 = __shfl(sj, j),     s1 = __shfl(sj, j + 1);
            int s2 = __shfl(sj, j + 2), s3 = __shfl(sj, j + 3);
            int s4 = __shfl(sj, j + 4), s5 = __shfl(sj, j + 5);
            int s6 = __shfl(sj, j + 6), s7 = __shfl(sj, j + 7);
            uint v0 = xb[(size_t)s0 * 64 + lane], v1 = xb[(size_t)s1 * 64 + lane];
            uint v2 = xb[(size_t)s2 * 64 + lane], v3 = xb[(size_t)s3 * 64 + lane];
            uint v4 = xb[(size_t)s4 * 64 + lane], v5 = xb[(size_t)s5 * 64 + lane];
            uint v6 = xb[(size_t)s6 * 64 + lane], v7 = xb[(size_t)s7 * 64 + lane];
            a0 += blo(v0) + blo(v1) + blo(v2) + blo(v3)
                + blo(v4) + blo(v5) + blo(v6) + blo(v7);
            a1 += bhi(v0) + bhi(v1) + bhi(v2) + bhi(v3)
                + bhi(v4) + bhi(v5) + bhi(v6) + bhi(v7);
        }
        for (; j < m; ++j) {
            int s = __shfl(sj, j);
            uint v = xb[(size_t)s * 64 + lane];
            a0 += blo(v); a1 += bhi(v);
        }
    }
    uint pk = (uint)f2bf(a0) | ((uint)f2bf(a1) << 16);
    ((uint*)(agg + (size_t)n * DD))[lane] = pk;
}

// MODE 1: A = bf16 agg, no pre-transform, bias, bf16 out, emit colstats
// MODE 2: A = bf16 t1,  BN coefs computed in-block from statsIn/g/be, relu(a*t+c),
//         bias, bf16 out, emit colstats
// MODE 3: A = bf16 t2,  same in-block BN, no bias, relu output, fp32 out, no stats
template <int MODE>
__global__ __launch_bounds__(256) void k_gemm(const ushort* __restrict__ Ain,
                                              const float* __restrict__ W,
                                              const float* __restrict__ bias,
                                              const float* __restrict__ statsIn,
                                              const float* __restrict__ g,
                                              const float* __restrict__ be,
                                              void* __restrict__ Outv,
                                              float* __restrict__ statsOut) {
    __shared__ ushort lw[DD * 136];
    __shared__ float red[2][4][DD];
    __shared__ float lac[2 * DD];

    int tid = threadIdx.x;
#pragma unroll
    for (int it = 0; it < 8; ++it) {
        int idx = (it * 256 + tid) * 8;
        int r = idx >> 7, k = idx & 127;
        float4 u0 = *(const float4*)(W + idx);
        float4 u1 = *(const float4*)(W + idx + 4);
        uint4 pk;
        pk.x = (uint)f2bf(u0.x) | ((uint)f2bf(u0.y) << 16);
        pk.y = (uint)f2bf(u0.z) | ((uint)f2bf(u0.w) << 16);
        pk.z = (uint)f2bf(u1.x) | ((uint)f2bf(u1.y) << 16);
        pk.w = (uint)f2bf(u1.z) | ((uint)f2bf(u1.w) << 16);
        *(uint4*)&lw[r * 136 + k] = pk;
    }
    if constexpr (MODE != 1) {
        if (tid < DD) {
            float inv = 1.f / (float)NN;
            float mean = statsIn[tid] * inv;
            float var = statsIn[DD + tid] * inv - mean * mean;
            float a = g[tid] * rsqrtf(var + 1e-5f);
            lac[tid] = a;
            lac[DD + tid] = be[tid] - mean * a;
        }
    }
    __syncthreads();

    int wave = tid >> 6, lane = tid & 63;
    int lm = lane & 15, quad = lane >> 4;
    int row0 = blockIdx.x * 64 + wave * 16;
    int arow = row0 + lm;
    int ar = (arow < NN) ? arow : 0;

    bf16x8 afrag[4];
#pragma unroll
    for (int kb = 0; kb < 4; ++kb) {
        int k0 = kb * 32 + quad * 8;
        const ushort* ap = Ain + (size_t)ar * DD + k0;
        u4bf8 u; u.u = *(const uint4*)ap;
        if constexpr (MODE == 1) {
            afrag[kb] = u.v;
        } else {
            uint pk[4] = {u.u.x, u.u.y, u.u.z, u.u.w};
            bf16x8 af;
#pragma unroll
            for (int jj = 0; jj < 4; ++jj) {
                int k = k0 + jj * 2;
                float v0 = blo(pk[jj]);
                float v1 = bhi(pk[jj]);
                v0 = fmaxf(fmaf(v0, lac[k], lac[DD + k]), 0.f);
                v1 = fmaxf(fmaf(v1, lac[k + 1], lac[DD + k + 1]), 0.f);
                af[jj * 2]     = (short)f2bf(v0);
                af[jj * 2 + 1] = (short)f2bf(v1);
            }
            afrag[kb] = af;
        }
    }

    f32x4 acc[8];
#pragma unroll
    for (int nt = 0; nt < 8; ++nt) {
        float bv = (MODE == 3) ? 0.f : bias[nt * 16 + lm];
        acc[nt] = (f32x4){bv, bv, bv, bv};
    }

#pragma unroll
    for (int kb = 0; kb < 4; ++kb) {
#pragma unroll
        for (int nt = 0; nt < 8; ++nt) {
            bf16x8 bfrag = *(const bf16x8*)&lw[(nt * 16 + lm) * 136 + kb * 32 + quad * 8];
            acc[nt] = __builtin_amdgcn_mfma_f32_16x16x32_bf16(afrag[kb], bfrag, acc[nt], 0, 0, 0);
        }
    }

    ushort* Out16 = (ushort*)Outv;
    float* Out32 = (float*)Outv;
    float csum[8], csq[8];
#pragma unroll
    for (int nt = 0; nt < 8; ++nt) {
        int col = nt * 16 + lm;
        float s = 0.f, q = 0.f;
#pragma unroll
        for (int r = 0; r < 4; ++r) {
            int row = row0 + quad * 4 + r;
            float v = acc[nt][r];
            if (MODE == 3) v = fmaxf(v, 0.f);
            if (row < NN) {
                if constexpr (MODE == 3) Out32[(size_t)row * DD + col] = v;
                else Out16[(size_t)row * DD + col] = f2bf(v);
                s += v;
                q += v * v;
            }
        }
        csum[nt] = s; csq[nt] = q;
    }

    if constexpr (MODE != 3) {
#pragma unroll
        for (int nt = 0; nt < 8; ++nt) {
            float s = csum[nt], q = csq[nt];
            s += __shfl_down(s, 16, 64); q += __shfl_down(q, 16, 64);
            s += __shfl_down(s, 32, 64); q += __shfl_down(q, 32, 64);
            if (quad == 0) {
                red[0][wave][nt * 16 + lm] = s;
                red[1][wave][nt * 16 + lm] = q;
            }
        }
        __syncthreads();
        if (tid < DD) {
            float S = red[0][0][tid] + red[0][1][tid] + red[0][2][tid] + red[0][3][tid];
            float Q = red[1][0][tid] + red[1][1][tid] + red[1][2][tid] + red[1][3][tid];
            atomicAdd(&statsOut[tid], S);
            atomicAdd(&statsOut[DD + tid], Q);
        }
    }
}

extern "C" void kernel_launch(void* const* d_in, const int* in_sizes, int n_in,
                              void* d_out, int out_size, void* d_ws, size_t ws_size,
                              hipStream_t stream) {
    const float* x   = (const float*)d_in[0];
    const int* ei    = (const int*)d_in[1];
    const float* W1  = (const float*)d_in[2];
    const float* b1  = (const float*)d_in[3];
    const float* g1  = (const float*)d_in[4];
    const float* be1 = (const float*)d_in[5];
    const float* W2  = (const float*)d_in[6];
    const float* b2  = (const float*)d_in[7];
    const float* g2  = (const float*)d_in[8];
    const float* be2 = (const float*)d_in[9];
    const float* W3  = (const float*)d_in[10];

    // ws: stats[512] | ghistP[NCB*16] | cb[NCB+4] | gcurP[NCB*16]
    //   | rowp i32[NCB*512+4] | buck u32[NE] | csr i32[NE]
    //   | agg bf16[NN*DD] (reused as t2)        ~39 MB
    float* stats = (float*)d_ws;
    int* ghistP  = (int*)(stats + 512);
    int* cb      = ghistP + NCB * 16;
    int* gcurP   = cb + NCB + 4;
    int* rowp    = gcurP + NCB * 16;
    uint* buck   = (uint*)(rowp + NCB * 512 + 4);
    int* csr     = (int*)(buck + NE);
    ushort* agg  = (ushort*)(csr + NE);
    // d_out: first half = xb (bf16 x copy), second half = t1
    uint* xb     = (uint*)d_out;
    ushort* t1   = (ushort*)d_out + (size_t)NN * DD;
    ushort* t2   = agg;
    float* outp  = (float*)d_out;

    int gblk = (NN + 63) / 64;
    hipMemsetAsync(stats, 0, (512 + NCB * 16) * sizeof(int), stream);
    k_xbh<<<NTILE, 256, 0, stream>>>(x, xb, ei, ghistP);
    k_cscan<<<1, 256, 0, stream>>>(ghistP, cb, gcurP);
    k_cscatter<<<NTILE, 256, 0, stream>>>(ei, gcurP, buck);
    k_fsort<<<NCB, 256, 0, stream>>>(buck, cb, csr, rowp);
    k_gather<<<(NN + 3) / 4, 256, 0, stream>>>(xb, rowp, csr, agg);
    k_gemm<1><<<gblk, 256, 0, stream>>>(agg, W1, b1, nullptr, nullptr, nullptr, t1, stats);
    k_gemm<2><<<gblk, 256, 0, stream>>>(t1, W2, b2, stats, g1, be1, t2, stats + 256);
    k_gemm<3><<<gblk, 256, 0, stream>>>(t2, W3, nullptr, stats + 256, g2, be2, outp, nullptr);
}